// Round 10
// baseline (227.143 us; speedup 1.0000x reference)
//
#include <hip/hip_runtime.h>

#define N_PTS 32768
#define M_PTS 8192      // N / STRIDE
#define C_IN  64
#define C_OUT 128
#define KNN   16
#define GDIM  67        // 3 + C_IN
#define BN_EPS 1e-5f
#define MAXC  64        // centers with candidate/hbuf fast path
#define NBLK  8         // mega-kernel blocks (co-resident, grid barrier)

// workspace offsets (bytes)
#define OFF_META  32768u      // int[8]: [0]=nuniq [1]=cycStart [2]=cycLen
#define OFF_KNN   33024u      // int[M_PTS*KNN] (fallback use only)
#define OFF_CAND  557312u     // u64[MAXC*2048]
#define OFF_HBUF  1605888u    // float[MAXC*KNN*C_OUT]
#define OFF_PART  2130176u    // float[NBLK*256]
#define OFF_SCALE 2138368u    // float[C_OUT]
#define OFF_SHIFT 2138880u    // float[C_OUT]
#define OFF_SYNC  2139392u    // int cnt; +64: int sense; +128: u64 winners[16]

typedef unsigned int uint32;
typedef unsigned long long uint64;

// multiplicity of unique slot s in the length-M periodic index sequence
__device__ __forceinline__ int slot_count(int s, int nun, int cs, int cl, int M) {
    if (s < cs) return 1;
    const int E = M - nun;
    const int base = E / cl, rem = E % cl;
    const int start = (nun - cs) % cl;
    int off = (s - cs) - start; if (off < 0) off += cl;
    return 1 + base + (off < rem ? 1 : 0);
}

__device__ __forceinline__ uint32 dist_key(float d) {
    uint32 u = __float_as_uint(d);
    return (u & 0x80000000u) ? ~u : (u | 0x80000000u);
}

__device__ __forceinline__ void grid_barrier(int* cnt, int* sense, int tid,
                                             int* s_sense) {
    __threadfence();
    __syncthreads();
    if (tid == 0) {
        const int ns = *s_sense ^ 1;
        *s_sense = ns;
        int prev = __hip_atomic_fetch_add(cnt, 1, __ATOMIC_ACQ_REL,
                                          __HIP_MEMORY_SCOPE_AGENT);
        if (prev == NBLK - 1) {
            __hip_atomic_store(cnt, 0, __ATOMIC_RELAXED, __HIP_MEMORY_SCOPE_AGENT);
            __hip_atomic_store(sense, ns, __ATOMIC_RELEASE, __HIP_MEMORY_SCOPE_AGENT);
        } else {
            while (__hip_atomic_load(sense, __ATOMIC_ACQUIRE,
                                     __HIP_MEMORY_SCOPE_AGENT) != ns)
                __builtin_amdgcn_s_sleep(8);
        }
    }
    __syncthreads();
    __threadfence();
}

// ---- mega: fps chain + newp + knn partials + merge + h/stats + BN finalize ----
__global__ void __launch_bounds__(1024) mega_kernel(const float* __restrict__ p,
                                                    const float* __restrict__ x,
                                                    const float* __restrict__ W,
                                                    const float* __restrict__ gamma,
                                                    const float* __restrict__ beta,
                                                    int* __restrict__ meta,
                                                    uint64* __restrict__ cand,
                                                    int* __restrict__ knn,
                                                    float* __restrict__ hbuf,
                                                    float* __restrict__ part,
                                                    float* __restrict__ scale,
                                                    float* __restrict__ shift,
                                                    float* __restrict__ newp,
                                                    int* __restrict__ sync_cnt,
                                                    int* __restrict__ sync_sense,
                                                    uint64* __restrict__ winners) {
    const int tid  = threadIdx.x;
    const int blk  = blockIdx.x;
    const int lane = tid & 63;
    const int wid  = tid >> 6;              // 16 waves
    const int i0   = (blk << 12) + (tid << 2);  // 4 contiguous points/thread

    __shared__ int    s_chain[M_PTS];       // 32 KB
    __shared__ uint64 wv_p[16];
    __shared__ uint64 s_best;
    __shared__ int    s_sense, s_win, s_found;
    __shared__ int    sknn[KNN];
    __shared__ float  gbuf[GDIM + 1];

    // register-cache this thread's 4 points (12 VGPRs)
    float P[4][3];
#pragma unroll
    for (int j = 0; j < 4; ++j) {
        P[j][0] = p[3*(i0+j)]; P[j][1] = p[3*(i0+j)+1]; P[j][2] = p[3*(i0+j)+2];
    }

    if (tid == 0) { s_chain[0] = 0; s_sense = 0; }
    __syncthreads();

    // ---------- phase 1: FPS chain (serial steps, grid-parallel scan) ----------
    int last = 0, t = 1, csv = 0, clv = 1;
    bool done = false;
    while (t < M_PTS) {
        const float qx = p[3*last], qy = p[3*last+1], qz = p[3*last+2];
        uint64 best = 0ull;
#pragma unroll
        for (int j = 0; j < 4; ++j) {
            // match numpy: ((dx^2+dy^2)+dz^2), no contraction
            float dx = __fsub_rn(P[j][0], qx);
            float dy = __fsub_rn(P[j][1], qy);
            float dz = __fsub_rn(P[j][2], qz);
            float d  = __fadd_rn(__fadd_rn(__fmul_rn(dx,dx), __fmul_rn(dy,dy)),
                                 __fmul_rn(dz,dz));
            // max-key: larger d wins; equal d -> smaller idx wins
            uint64 key = ((uint64)__float_as_uint(d) << 32)
                       | (uint32)(0xFFFFFFFFu - (uint32)(i0 + j));
            if (key > best) best = key;
        }
#pragma unroll
        for (int off = 32; off > 0; off >>= 1) {
            uint64 o = __shfl_xor(best, off);
            if (o > best) best = o;
        }
        if (lane == 0) wv_p[wid] = best;
        __syncthreads();
        if (wid == 0) {
            uint64 b2 = (lane < 16) ? wv_p[lane] : 0ull;
#pragma unroll
            for (int off = 8; off > 0; off >>= 1) {
                uint64 o = __shfl_xor(b2, off);
                if (o > b2) b2 = o;
            }
            if (lane == 0)
                __hip_atomic_store(&winners[(t & 1)*NBLK + blk], b2,
                                   __ATOMIC_RELAXED, __HIP_MEMORY_SCOPE_AGENT);
        }
        grid_barrier(sync_cnt, sync_sense, tid, &s_sense);
        if (tid == 0) {
            uint64 g = 0ull;
#pragma unroll
            for (int b = 0; b < NBLK; ++b) {
                uint64 w = __hip_atomic_load(&winners[(t & 1)*NBLK + b],
                                             __ATOMIC_RELAXED,
                                             __HIP_MEMORY_SCOPE_AGENT);
                if (w > g) g = w;
            }
            s_win = (int)(0xFFFFFFFFu - (uint32)(g & 0xFFFFFFFFull));
            s_found = -1;
        }
        __syncthreads();
        const int nxt = s_win;
        for (int i = tid; i < t; i += 1024)
            if (s_chain[i] == nxt) s_found = i;   // entries unique: <=1 writer
        __syncthreads();
        if (s_found >= 0) { done = true; csv = s_found; break; }
        if (tid == 0) s_chain[t] = nxt;
        __syncthreads();
        last = nxt; ++t;
    }
    const int nun = done ? t : M_PTS;
    if (done) clv = t - csv; else { csv = 0; clv = 1; }

    if (blk == 0 && tid == 0) { meta[0] = nun; meta[1] = csv; meta[2] = clv; }

    // ---------- phase 2: newp fill (one row per thread, 8192 threads) ----------
    {
        const int e  = (blk << 10) + tid;
        const int sl = (e < nun) ? e : csv + (e - csv) % clv;
        const int id = s_chain[sl];
        newp[3*e]   = p[3*id];
        newp[3*e+1] = p[3*id+1];
        newp[3*e+2] = p[3*id+2];
    }

    // ---------- phase 3: kNN partials (block = slice; per-wave top-16) ----------
    const int cmax = (nun < MAXC) ? nun : MAXC;
    for (int c = 0; c < cmax; ++c) {
        const int cpt = s_chain[c];
        const float qx = p[3*cpt], qy = p[3*cpt+1], qz = p[3*cpt+2];
        uint64 pk4[4];
#pragma unroll
        for (int j = 0; j < 4; ++j) {
            float dx = P[j][0] - qx;
            float dy = P[j][1] - qy;
            float dz = P[j][2] - qz;
            float d  = fmaf(dx, dx, fmaf(dy, dy, dz*dz));
            pk4[j] = ((uint64)dist_key(d) << 32) | (uint32)(i0 + j);
        }
        uint64 lastv = 0ull;
        uint64* outp = cand + ((size_t)c << 11) + (blk << 8) + (wid << 4);
        for (int r = 0; r < KNN; ++r) {
            uint64 m = ~0ull;
#pragma unroll
            for (int j = 0; j < 4; ++j) {
                const uint64 v = pk4[j];
                if (v > lastv && v < m) m = v;
            }
#pragma unroll
            for (int off = 32; off > 0; off >>= 1) {
                uint64 o = __shfl_xor(m, off);
                if (o < m) m = o;
            }
            if (lane == 0) outp[r] = m;
            lastv = m;
        }
    }
    grid_barrier(sync_cnt, sync_sense, tid, &s_sense);

    // ---------- phase 4: merge + h + weighted stats (centers strided by block) --
    float acc_sum = 0.f, acc_sq = 0.f;
    for (int c = blk; c < nun; c += NBLK) {
        uint64 kc0 = 0ull, kc1 = 0ull;
        float sqx = 0.f, sqy = 0.f, sqz = 0.f;
        if (c < MAXC) {
            const uint64* src = cand + ((size_t)c << 11);
            kc0 = src[tid]; kc1 = src[tid + 1024];
        } else {
            const int cpt = s_chain[c];
            sqx = p[3*cpt]; sqy = p[3*cpt+1]; sqz = p[3*cpt+2];
        }
        uint64 lastv = 0ull;
        for (int r = 0; r < KNN; ++r) {
            uint64 m = ~0ull;
            if (c < MAXC) {
                if (kc0 > lastv && kc0 < m) m = kc0;
                if (kc1 > lastv && kc1 < m) m = kc1;
            } else {
                for (int i = tid; i < N_PTS; i += 1024) {
                    float dx = p[3*i]   - sqx;
                    float dy = p[3*i+1] - sqy;
                    float dz = p[3*i+2] - sqz;
                    float d  = fmaf(dx, dx, fmaf(dy, dy, dz*dz));
                    uint64 v = ((uint64)dist_key(d) << 32) | (uint32)i;
                    if (v > lastv && v < m) m = v;
                }
            }
#pragma unroll
            for (int off = 32; off > 0; off >>= 1) {
                uint64 o = __shfl_xor(m, off);
                if (o < m) m = o;
            }
            if (lane == 0) wv_p[wid] = m;
            __syncthreads();
            if (wid == 0) {
                uint64 b2 = (lane < 16) ? wv_p[lane] : ~0ull;
#pragma unroll
                for (int off = 8; off > 0; off >>= 1) {
                    uint64 o = __shfl_xor(b2, off);
                    if (o < b2) b2 = o;
                }
                if (lane == 0) {
                    s_best = b2;
                    const int wi = (int)(b2 & 0xFFFFFFFFull);
                    sknn[r] = wi;
                    knn[c*KNN + r] = wi;
                }
            }
            __syncthreads();
            lastv = s_best;
        }

        float ls = 0.f, lq = 0.f;
#pragma unroll
        for (int k = 0; k < KNN; ++k) {
            const int pt = sknn[k];
            if (tid < GDIM) gbuf[tid] = (tid < 3) ? p[3*pt + tid]
                                                  : x[(pt << 6) + tid - 3];
            __syncthreads();
            if (tid < C_OUT) {
                float a = 0.f;
#pragma unroll
                for (int cc = 0; cc < GDIM; ++cc)
                    a = fmaf(gbuf[cc], W[cc*C_OUT + tid], a);
                if (c < MAXC) hbuf[((c << 4) + k)*C_OUT + tid] = a;
                ls += a;
                lq = fmaf(a, a, lq);
            }
            __syncthreads();
        }
        const float cf = (float)slot_count(c, nun, csv, clv, M_PTS);
        if (tid < C_OUT) {
            acc_sum = fmaf(cf, ls, acc_sum);
            acc_sq  = fmaf(cf, lq, acc_sq);
        }
    }
    if (tid < C_OUT) {
        part[blk*256 + tid]       = acc_sum;
        part[blk*256 + 128 + tid] = acc_sq;
    }
    grid_barrier(sync_cnt, sync_sense, tid, &s_sense);

    // ---------- phase 5: BN finalize (block 0) ----------
    if (blk == 0 && tid < C_OUT) {
        float s = 0.f, q = 0.f;
#pragma unroll
        for (int b = 0; b < NBLK; ++b) {
            s += part[b*256 + tid];
            q += part[b*256 + 128 + tid];
        }
        const float inv  = 1.0f / (float)(M_PTS * KNN);
        const float mean = s * inv;
        const float var  = q * inv - mean*mean;
        const float sc   = gamma[tid] * rsqrtf(var + BN_EPS);
        scale[tid] = sc;
        shift[tid] = fmaf(-mean, sc, beta[tid]);
    }
}

// ---- final: all M rows from cached h: BN + relu + maxpool, write xout --------
__global__ void __launch_bounds__(256) final_out_kernel(const float* __restrict__ p,
                                                        const float* __restrict__ x,
                                                        const float* __restrict__ W,
                                                        const int* __restrict__ knn,
                                                        const int* __restrict__ meta,
                                                        const float* __restrict__ hbuf,
                                                        const float* __restrict__ scale,
                                                        const float* __restrict__ shift,
                                                        float* __restrict__ xout) {
    const int nun = meta[0], cs = meta[1], cl = meta[2];
    const int idx = blockIdx.x * 256 + threadIdx.x;
    const int m = idx >> 5;
    if (m >= M_PTS) return;
    const int c4 = idx & 31;
    const int sl = (m < nun) ? m : cs + (m - cs) % cl;

    float4 o;
    float* ov = (float*)&o;
    if (sl < MAXC) {
        const float* hb = hbuf + (sl << 4)*C_OUT;
#pragma unroll
        for (int cc = 0; cc < 4; ++cc) {
            const int ch = c4*4 + cc;
            const float sc = scale[ch], sh = shift[ch];
            float mx = 0.f;
#pragma unroll
            for (int k = 0; k < KNN; ++k)
                mx = fmaxf(mx, fmaf(hb[k*C_OUT + ch], sc, sh));
            ov[cc] = mx;
        }
    } else {
#pragma unroll
        for (int cc = 0; cc < 4; ++cc) {
            const int ch = c4*4 + cc;
            const float sc = scale[ch], sh = shift[ch];
            float mx = 0.f;
            for (int k = 0; k < KNN; ++k) {
                const int pt = knn[sl*KNN + k];
                float acc = 0.f;
                acc = fmaf(p[3*pt],   W[0*C_OUT + ch], acc);
                acc = fmaf(p[3*pt+1], W[1*C_OUT + ch], acc);
                acc = fmaf(p[3*pt+2], W[2*C_OUT + ch], acc);
                for (int cx = 0; cx < C_IN; ++cx)
                    acc = fmaf(x[(pt << 6) + cx], W[(3+cx)*C_OUT + ch], acc);
                mx = fmaxf(mx, fmaf(acc, sc, sh));
            }
            ov[cc] = mx;
        }
    }
    ((float4*)xout)[(size_t)m*32 + c4] = o;
}

extern "C" void kernel_launch(void* const* d_in, const int* in_sizes, int n_in,
                              void* d_out, int out_size, void* d_ws, size_t ws_size,
                              hipStream_t stream) {
    (void)in_sizes; (void)n_in; (void)out_size; (void)ws_size;
    const float* p     = (const float*)d_in[0];
    const float* x     = (const float*)d_in[1];
    // d_in[2] = o (unused)
    const float* W     = (const float*)d_in[3];
    const float* gamma = (const float*)d_in[4];
    const float* beta  = (const float*)d_in[5];

    float* out  = (float*)d_out;
    float* newp = out;               // [M_PTS, 3]
    float* xout = out + M_PTS * 3;   // [M_PTS, C_OUT]

    char* ws = (char*)d_ws;
    int*    meta  = (int*)   (ws + OFF_META);
    int*    knn   = (int*)   (ws + OFF_KNN);
    uint64* cand  = (uint64*)(ws + OFF_CAND);
    float*  hbuf  = (float*) (ws + OFF_HBUF);
    float*  part  = (float*) (ws + OFF_PART);
    float*  scale = (float*) (ws + OFF_SCALE);
    float*  shift = (float*) (ws + OFF_SHIFT);
    int*    scnt  = (int*)   (ws + OFF_SYNC);
    int*    ssns  = (int*)   (ws + OFF_SYNC + 64);
    uint64* winrs = (uint64*)(ws + OFF_SYNC + 128);

    hipMemsetAsync(ws + OFF_SYNC, 0, 256, stream);   // barrier state per call
    mega_kernel<<<NBLK, 1024, 0, stream>>>(p, x, W, gamma, beta, meta, cand, knn,
                                           hbuf, part, scale, shift, newp,
                                           scnt, ssns, winrs);
    final_out_kernel<<<M_PTS*32/256, 256, 0, stream>>>(p, x, W, knn, meta, hbuf,
                                                       scale, shift, xout);
}

// Round 11
// 100.809 us; speedup vs baseline: 2.2532x; 2.2532x over previous
//
#include <hip/hip_runtime.h>

#define N_PTS 32768
#define M_PTS 8192      // N / STRIDE
#define C_IN  64
#define C_OUT 128
#define KNN   16
#define GDIM  67        // 3 + C_IN
#define BN_EPS 1e-5f
#define MAXC  64        // centers with candidate/hbuf fast path

// workspace offsets (bytes)
#define OFF_FPS   0u          // int[M_PTS] (only first nuniq used)
#define OFF_META  32768u      // int[8]: [0]=nuniq [1]=cycStart [2]=cycLen
#define OFF_KNN   33024u      // int[M_PTS*KNN]
#define OFF_CAND  557312u     // u64[MAXC*2048]
#define OFF_HBUF  1605888u    // float[MAXC*KNN*C_OUT]
#define OFF_UROW  2129920u    // float[M_PTS*C_OUT] (pooled unique rows)

typedef unsigned int uint32;
typedef unsigned long long uint64;

// multiplicity of unique slot s in the length-M periodic index sequence
__device__ __forceinline__ int slot_count(int s, int nun, int cs, int cl, int M) {
    if (s < cs) return 1;                 // pre-cycle slot: occurs once
    const int E = M - nun;                // extended (periodic) occurrences
    const int base = E / cl, rem = E % cl;
    const int start = (nun - cs) % cl;    // residue of first extended index
    int off = (s - cs) - start; if (off < 0) off += cl;
    return 1 + base + (off < rem ? 1 : 0);
}

__device__ __forceinline__ uint32 dist_key(float d) {
    uint32 u = __float_as_uint(d);
    return (u & 0x80000000u) ? ~u : (u | 0x80000000u);
}

// ---------------- FPS chain only: serial argmax steps, LDS chain ----------------
__global__ void __launch_bounds__(1024) fps_chain_kernel(const float* __restrict__ p,
                                                         int* __restrict__ fps,
                                                         int* __restrict__ meta) {
    __shared__ int   s_chain[M_PTS];     // 32 KB
    __shared__ float wv_d[16];
    __shared__ int   wv_i[16];
    __shared__ int s_last, s_done, s_cs, s_win, s_found;
    const int tid  = threadIdx.x;
    const int lane = tid & 63;
    const int wid  = tid >> 6;

    if (tid == 0) { s_chain[0] = 0; s_last = 0; s_done = 0; s_cs = 0; }
    __syncthreads();

    int t = 1;
    while (t < M_PTS) {
        const int last = s_last;
        const float qx = p[3*last], qy = p[3*last+1], qz = p[3*last+2];
        float bd = -1.0f; int bi = 0;
#pragma unroll
        for (int j = 0; j < 32; ++j) {
            const int i = tid + (j << 10);
            // match numpy: ((dx^2 + dy^2) + dz^2), no FMA contraction
            float dx = __fsub_rn(p[3*i],   qx);
            float dy = __fsub_rn(p[3*i+1], qy);
            float dz = __fsub_rn(p[3*i+2], qz);
            float d  = __fadd_rn(__fadd_rn(__fmul_rn(dx,dx), __fmul_rn(dy,dy)),
                                 __fmul_rn(dz,dz));
            if (d > bd) { bd = d; bi = i; }   // ascending i keeps first on ties
        }
#pragma unroll
        for (int off = 32; off > 0; off >>= 1) {
            float od = __shfl_xor(bd, off);
            int   oi = __shfl_xor(bi, off);
            if (od > bd || (od == bd && oi < bi)) { bd = od; bi = oi; }
        }
        if (lane == 0) { wv_d[wid] = bd; wv_i[wid] = bi; }
        __syncthreads();
        if (wid == 0) {
            float rd = (lane < 16) ? wv_d[lane] : -1.0f;
            int   ri = (lane < 16) ? wv_i[lane] : 0x7fffffff;
#pragma unroll
            for (int off = 8; off > 0; off >>= 1) {
                float od = __shfl_xor(rd, off);
                int   oi = __shfl_xor(ri, off);
                if (od > rd || (od == rd && oi < ri)) { rd = od; ri = oi; }
            }
            if (lane == 0) { s_win = ri; s_found = -1; }
        }
        __syncthreads();
        const int nxt = s_win;
        for (int i = tid; i < t; i += 1024)
            if (s_chain[i] == nxt) s_found = i;
        __syncthreads();
        if (tid == 0) {
            if (s_found >= 0) { s_cs = s_found; s_done = 1; }
            else { s_chain[t] = nxt; s_last = nxt; }
        }
        __syncthreads();
        if (s_done) break;
        ++t;
    }

    if (tid == 0) {
        if (s_done) { meta[0] = t; meta[1] = s_cs; meta[2] = t - s_cs; }
        else        { meta[0] = M_PTS; meta[1] = 0; meta[2] = 1; }
    }
    const int nun = s_done ? t : M_PTS;
    for (int i = tid; i < nun; i += 1024) fps[i] = s_chain[i];
}

// ---- kNN phase A (+ parallel newp fill): 8 slices/center, per-wave top-16 ------
__global__ void __launch_bounds__(1024) knn_part_kernel(const float* __restrict__ p,
                                                        const int* __restrict__ fps,
                                                        const int* __restrict__ meta,
                                                        uint64* __restrict__ cand,
                                                        float* __restrict__ newp) {
    const int tid   = threadIdx.x;
    const int lane  = tid & 63;
    const int wid   = tid >> 6;           // 16 waves
    const int slice = blockIdx.x & 7;
    const int c0    = blockIdx.x >> 3;    // 16 center groups
    const int nun   = meta[0];
    const int cs    = meta[1], cl = meta[2];

    // parallel newp fill
    for (int e = blockIdx.x * 1024 + tid; e < M_PTS; e += gridDim.x * 1024) {
        const int sl = (e < nun) ? e : cs + (e - cs) % cl;
        const int id = fps[sl];
        newp[3*e]   = p[3*id];
        newp[3*e+1] = p[3*id+1];
        newp[3*e+2] = p[3*id+2];
    }

    for (int c = c0; c < nun && c < MAXC; c += 16) {
        const int cpt = fps[c];
        const float qx = p[3*cpt], qy = p[3*cpt+1], qz = p[3*cpt+2];
        const int base = slice << 12;     // slice*4096

        uint64 pk4[4];
#pragma unroll
        for (int j = 0; j < 4; ++j) {
            const int i = base + tid + (j << 10);
            float dx = p[3*i]   - qx;
            float dy = p[3*i+1] - qy;
            float dz = p[3*i+2] - qz;
            float d  = fmaf(dx, dx, fmaf(dy, dy, dz*dz));
            pk4[j] = ((uint64)dist_key(d) << 32) | (uint32)i;
        }

        uint64 lastv = 0ull;
        uint64* out = cand + ((size_t)c << 11) + (slice << 8) + (wid << 4);
        for (int r = 0; r < KNN; ++r) {
            uint64 m = ~0ull;
#pragma unroll
            for (int j = 0; j < 4; ++j) {
                const uint64 v = pk4[j];
                if (v > lastv && v < m) m = v;
            }
#pragma unroll
            for (int off = 32; off > 0; off >>= 1) {
                uint64 o = __shfl_xor(m, off);
                if (o < m) m = o;
            }
            if (lane == 0) out[r] = m;
            lastv = m;
        }
    }
}

// ---- fused tail: single block x 128 threads (thread == channel).
// Sequentially per center: merge 2048 cands -> knn, compute h once (-> hbuf),
// accumulate full weighted stats IN REGISTERS (single block => no partials),
// then BN finalize in-register and emit pooled unique rows urow. ----
__global__ void __launch_bounds__(128) tail_kernel(const float* __restrict__ p,
                                                   const float* __restrict__ x,
                                                   const float* __restrict__ W,
                                                   const float* __restrict__ gamma,
                                                   const float* __restrict__ beta,
                                                   const int* __restrict__ fps,
                                                   const int* __restrict__ meta,
                                                   const uint64* __restrict__ cand,
                                                   int* __restrict__ knn,
                                                   float* __restrict__ hbuf,
                                                   float* __restrict__ urow) {
    const int tid  = threadIdx.x;       // == channel
    const int lane = tid & 63;
    const int wv   = tid >> 6;          // 2 waves
    const int nun  = meta[0], cs = meta[1], cl = meta[2];

    __shared__ int    sknn[KNN];
    __shared__ uint64 wmin[2];
    __shared__ uint64 s_win;
    __shared__ float  gbuf[GDIM + 1];

    float s_sum = 0.f, s_sq = 0.f;

    // ---- pass 1: merge + h + weighted stats ----
    for (int c = 0; c < nun; ++c) {
        if (c < MAXC) {
            uint64 kc[16];
            const uint64* src = cand + ((size_t)c << 11);
#pragma unroll
            for (int j = 0; j < 16; ++j) kc[j] = src[tid + (j << 7)];
            uint64 lastv = 0ull;
            for (int r = 0; r < KNN; ++r) {
                uint64 m = ~0ull;
#pragma unroll
                for (int j = 0; j < 16; ++j) {
                    const uint64 v = kc[j];
                    if (v > lastv && v < m) m = v;
                }
#pragma unroll
                for (int off = 32; off > 0; off >>= 1) {
                    uint64 o = __shfl_xor(m, off);
                    if (o < m) m = o;
                }
                if (lane == 0) wmin[wv] = m;
                __syncthreads();
                if (tid == 0) {
                    uint64 w = wmin[0] < wmin[1] ? wmin[0] : wmin[1];
                    s_win = w;
                    const int wi = (int)(w & 0xFFFFFFFFull);
                    sknn[r] = wi;
                    knn[c*KNN + r] = wi;
                }
                __syncthreads();
                lastv = s_win;
            }
        } else {
            // correct-but-slow fallback (never expected for this input)
            const int cpt = fps[c];
            const float qx = p[3*cpt], qy = p[3*cpt+1], qz = p[3*cpt+2];
            uint64 lastv = 0ull;
            for (int r = 0; r < KNN; ++r) {
                uint64 m = ~0ull;
                for (int i = tid; i < N_PTS; i += 128) {
                    float dx = p[3*i]   - qx;
                    float dy = p[3*i+1] - qy;
                    float dz = p[3*i+2] - qz;
                    float d  = fmaf(dx, dx, fmaf(dy, dy, dz*dz));
                    uint64 v = ((uint64)dist_key(d) << 32) | (uint32)i;
                    if (v > lastv && v < m) m = v;
                }
#pragma unroll
                for (int off = 32; off > 0; off >>= 1) {
                    uint64 o = __shfl_xor(m, off);
                    if (o < m) m = o;
                }
                if (lane == 0) wmin[wv] = m;
                __syncthreads();
                if (tid == 0) {
                    uint64 w = wmin[0] < wmin[1] ? wmin[0] : wmin[1];
                    s_win = w;
                    const int wi = (int)(w & 0xFFFFFFFFull);
                    sknn[r] = wi;
                    knn[c*KNN + r] = wi;
                }
                __syncthreads();
                lastv = s_win;
            }
        }

        float ls = 0.f, lq = 0.f;
#pragma unroll
        for (int k = 0; k < KNN; ++k) {
            const int pt = sknn[k];
            if (tid < GDIM) gbuf[tid] = (tid < 3) ? p[3*pt + tid]
                                                  : x[(pt << 6) + tid - 3];
            __syncthreads();
            float a = 0.f;
#pragma unroll
            for (int cc = 0; cc < GDIM; ++cc)
                a = fmaf(gbuf[cc], W[cc*C_OUT + tid], a);
            if (c < MAXC) hbuf[((c << 4) + k)*C_OUT + tid] = a;
            ls += a;
            lq = fmaf(a, a, lq);
            __syncthreads();
        }
        const float cf = (float)slot_count(c, nun, cs, cl, M_PTS);
        s_sum = fmaf(cf, ls, s_sum);
        s_sq  = fmaf(cf, lq, s_sq);
    }

    // ---- BN finalize in registers (thread == channel) ----
    const float inv  = 1.0f / (float)(M_PTS * KNN);
    const float mean = s_sum * inv;
    const float var  = s_sq * inv - mean*mean;
    const float sc   = gamma[tid] * rsqrtf(var + BN_EPS);
    const float sh   = fmaf(-mean, sc, beta[tid]);

    // ---- pass 2: pooled unique rows ----
    for (int c = 0; c < nun; ++c) {
        float mx = 0.f;   // max_k relu(y) == max(0, max_k y)
        if (c < MAXC) {
            const float* hb = hbuf + ((size_t)c << 4)*C_OUT;
#pragma unroll
            for (int k = 0; k < KNN; ++k)
                mx = fmaxf(mx, fmaf(hb[k*C_OUT + tid], sc, sh));
        } else {
#pragma unroll
            for (int k = 0; k < KNN; ++k) {
                const int pt = knn[c*KNN + k];
                if (tid < GDIM) gbuf[tid] = (tid < 3) ? p[3*pt + tid]
                                                      : x[(pt << 6) + tid - 3];
                __syncthreads();
                float a = 0.f;
#pragma unroll
                for (int cc = 0; cc < GDIM; ++cc)
                    a = fmaf(gbuf[cc], W[cc*C_OUT + tid], a);
                mx = fmaxf(mx, fmaf(a, sc, sh));
                __syncthreads();
            }
        }
        urow[c*C_OUT + tid] = mx;
    }
}

// ---- broadcast: xout[m] = urow[slot(m)] for all m (pure float4 copy) ----------
__global__ void __launch_bounds__(256) bcast_kernel(const int* __restrict__ meta,
                                                    const float* __restrict__ urow,
                                                    float* __restrict__ xout) {
    const int nun = meta[0], cs = meta[1], cl = meta[2];
    const int idx = blockIdx.x * 256 + threadIdx.x;      // float4 index
    const int m = idx >> 5;                              // 32 float4 per row
    if (m >= M_PTS) return;
    const int c4 = idx & 31;
    const int sl = (m < nun) ? m : cs + (m - cs) % cl;
    float4 v = ((const float4*)urow)[(size_t)sl*32 + c4];
    ((float4*)xout)[(size_t)m*32 + c4] = v;
}

extern "C" void kernel_launch(void* const* d_in, const int* in_sizes, int n_in,
                              void* d_out, int out_size, void* d_ws, size_t ws_size,
                              hipStream_t stream) {
    (void)in_sizes; (void)n_in; (void)out_size; (void)ws_size;
    const float* p     = (const float*)d_in[0];
    const float* x     = (const float*)d_in[1];
    // d_in[2] = o (unused)
    const float* W     = (const float*)d_in[3];
    const float* gamma = (const float*)d_in[4];
    const float* beta  = (const float*)d_in[5];

    float* out  = (float*)d_out;
    float* newp = out;               // [M_PTS, 3]
    float* xout = out + M_PTS * 3;   // [M_PTS, C_OUT]

    char* ws = (char*)d_ws;
    int*    fps   = (int*)   (ws + OFF_FPS);
    int*    meta  = (int*)   (ws + OFF_META);
    int*    knn   = (int*)   (ws + OFF_KNN);
    uint64* cand  = (uint64*)(ws + OFF_CAND);
    float*  hbuf  = (float*) (ws + OFF_HBUF);
    float*  urow  = (float*) (ws + OFF_UROW);

    fps_chain_kernel<<<1, 1024, 0, stream>>>(p, fps, meta);
    knn_part_kernel <<<128, 1024, 0, stream>>>(p, fps, meta, cand, newp);
    tail_kernel     <<<1, 128, 0, stream>>>(p, x, W, gamma, beta, fps, meta,
                                            cand, knn, hbuf, urow);
    bcast_kernel    <<<M_PTS*32/256, 256, 0, stream>>>(meta, urow, xout);
}

// Round 12
// 58.040 us; speedup vs baseline: 3.9135x; 1.7369x over previous
//
#include <hip/hip_runtime.h>

#define N_PTS 32768
#define M_PTS 8192      // N / STRIDE
#define C_IN  64
#define C_OUT 128
#define KNN   16
#define GDIM  67        // 3 + C_IN
#define BN_EPS 1e-5f
#define MAXC  64        // centers with candidate/hbuf fast path

// workspace offsets (bytes)
#define OFF_FPS   0u          // int[M_PTS] (only first nuniq used)
#define OFF_META  32768u      // int[8]: [0]=nuniq [1]=cycStart [2]=cycLen
#define OFF_KNN   33024u      // int[M_PTS*KNN] (fallback only)
#define OFF_CAND  557312u     // u64[MAXC*2048]
#define OFF_HBUF  1605888u    // float[MAXC*KNN*C_OUT]
#define OFF_UROW  2129920u    // float[M_PTS*C_OUT] (pooled unique rows)

typedef unsigned int uint32;
typedef unsigned long long uint64;

// multiplicity of unique slot s in the length-M periodic index sequence
__device__ __forceinline__ int slot_count(int s, int nun, int cs, int cl, int M) {
    if (s < cs) return 1;                 // pre-cycle slot: occurs once
    const int E = M - nun;                // extended (periodic) occurrences
    const int base = E / cl, rem = E % cl;
    const int start = (nun - cs) % cl;    // residue of first extended index
    int off = (s - cs) - start; if (off < 0) off += cl;
    return 1 + base + (off < rem ? 1 : 0);
}

__device__ __forceinline__ uint32 dist_key(float d) {
    uint32 u = __float_as_uint(d);
    return (u & 0x80000000u) ? ~u : (u | 0x80000000u);
}

// ---------------- FPS chain only: serial argmax steps, LDS chain ----------------
__global__ void __launch_bounds__(1024) fps_chain_kernel(const float* __restrict__ p,
                                                         int* __restrict__ fps,
                                                         int* __restrict__ meta) {
    __shared__ int   s_chain[M_PTS];     // 32 KB
    __shared__ float wv_d[16];
    __shared__ int   wv_i[16];
    __shared__ int s_last, s_done, s_cs, s_win, s_found;
    const int tid  = threadIdx.x;
    const int lane = tid & 63;
    const int wid  = tid >> 6;

    if (tid == 0) { s_chain[0] = 0; s_last = 0; s_done = 0; s_cs = 0; }
    __syncthreads();

    int t = 1;
    while (t < M_PTS) {
        const int last = s_last;
        const float qx = p[3*last], qy = p[3*last+1], qz = p[3*last+2];
        float bd = -1.0f; int bi = 0;
#pragma unroll
        for (int j = 0; j < 32; ++j) {
            const int i = tid + (j << 10);
            // match numpy: ((dx^2 + dy^2) + dz^2), no FMA contraction
            float dx = __fsub_rn(p[3*i],   qx);
            float dy = __fsub_rn(p[3*i+1], qy);
            float dz = __fsub_rn(p[3*i+2], qz);
            float d  = __fadd_rn(__fadd_rn(__fmul_rn(dx,dx), __fmul_rn(dy,dy)),
                                 __fmul_rn(dz,dz));
            if (d > bd) { bd = d; bi = i; }   // ascending i keeps first on ties
        }
#pragma unroll
        for (int off = 32; off > 0; off >>= 1) {
            float od = __shfl_xor(bd, off);
            int   oi = __shfl_xor(bi, off);
            if (od > bd || (od == bd && oi < bi)) { bd = od; bi = oi; }
        }
        if (lane == 0) { wv_d[wid] = bd; wv_i[wid] = bi; }
        __syncthreads();
        if (wid == 0) {
            float rd = (lane < 16) ? wv_d[lane] : -1.0f;
            int   ri = (lane < 16) ? wv_i[lane] : 0x7fffffff;
#pragma unroll
            for (int off = 8; off > 0; off >>= 1) {
                float od = __shfl_xor(rd, off);
                int   oi = __shfl_xor(ri, off);
                if (od > rd || (od == rd && oi < ri)) { rd = od; ri = oi; }
            }
            if (lane == 0) { s_win = ri; s_found = -1; }
        }
        __syncthreads();
        const int nxt = s_win;
        for (int i = tid; i < t; i += 1024)
            if (s_chain[i] == nxt) s_found = i;
        __syncthreads();
        if (tid == 0) {
            if (s_found >= 0) { s_cs = s_found; s_done = 1; }
            else { s_chain[t] = nxt; s_last = nxt; }
        }
        __syncthreads();
        if (s_done) break;
        ++t;
    }

    if (tid == 0) {
        if (s_done) { meta[0] = t; meta[1] = s_cs; meta[2] = t - s_cs; }
        else        { meta[0] = M_PTS; meta[1] = 0; meta[2] = 1; }
    }
    const int nun = s_done ? t : M_PTS;
    for (int i = tid; i < nun; i += 1024) fps[i] = s_chain[i];
}

// ---- kNN phase A (+ parallel newp fill): 8 slices/center, per-wave top-16 ------
__global__ void __launch_bounds__(1024) knn_part_kernel(const float* __restrict__ p,
                                                        const int* __restrict__ fps,
                                                        const int* __restrict__ meta,
                                                        uint64* __restrict__ cand,
                                                        float* __restrict__ newp) {
    const int tid   = threadIdx.x;
    const int lane  = tid & 63;
    const int wid   = tid >> 6;           // 16 waves
    const int slice = blockIdx.x & 7;
    const int c0    = blockIdx.x >> 3;    // 16 center groups
    const int nun   = meta[0];
    const int cs    = meta[1], cl = meta[2];

    // parallel newp fill
    for (int e = blockIdx.x * 1024 + tid; e < M_PTS; e += gridDim.x * 1024) {
        const int sl = (e < nun) ? e : cs + (e - cs) % cl;
        const int id = fps[sl];
        newp[3*e]   = p[3*id];
        newp[3*e+1] = p[3*id+1];
        newp[3*e+2] = p[3*id+2];
    }

    for (int c = c0; c < nun && c < MAXC; c += 16) {
        const int cpt = fps[c];
        const float qx = p[3*cpt], qy = p[3*cpt+1], qz = p[3*cpt+2];
        const int base = slice << 12;     // slice*4096

        uint64 pk4[4];
#pragma unroll
        for (int j = 0; j < 4; ++j) {
            const int i = base + tid + (j << 10);
            float dx = p[3*i]   - qx;
            float dy = p[3*i+1] - qy;
            float dz = p[3*i+2] - qz;
            float d  = fmaf(dx, dx, fmaf(dy, dy, dz*dz));
            pk4[j] = ((uint64)dist_key(d) << 32) | (uint32)i;
        }

        uint64 lastv = 0ull;
        uint64* out = cand + ((size_t)c << 11) + (slice << 8) + (wid << 4);
        for (int r = 0; r < KNN; ++r) {
            uint64 m = ~0ull;
#pragma unroll
            for (int j = 0; j < 4; ++j) {
                const uint64 v = pk4[j];
                if (v > lastv && v < m) m = v;
            }
#pragma unroll
            for (int off = 32; off > 0; off >>= 1) {
                uint64 o = __shfl_xor(m, off);
                if (o < m) m = o;
            }
            if (lane == 0) out[r] = m;
            lastv = m;
        }
    }
}

// ---- hstats: grid = MAXC x KNN blocks, 128 threads (thread == channel).
// Block (c,k): merge cand[c] via k+1 threshold-extraction rounds (bit-identical
// selection), load g for the k-th neighbor, h = g.W, write hbuf[c][k][ch]. ----
__global__ void __launch_bounds__(128) hstats_kernel(const float* __restrict__ p,
                                                     const float* __restrict__ x,
                                                     const float* __restrict__ W,
                                                     const int* __restrict__ meta,
                                                     const uint64* __restrict__ cand,
                                                     float* __restrict__ hbuf) {
    const int c = blockIdx.x >> 4;
    const int k = blockIdx.x & 15;
    const int nun = meta[0];
    if (c >= nun || c >= MAXC) return;
    const int tid  = threadIdx.x;
    const int lane = tid & 63;
    const int wv   = tid >> 6;

    __shared__ uint64 wmin[2];
    __shared__ uint64 s_win;
    __shared__ float  gbuf[GDIM + 1];

    uint64 kc[16];
    const uint64* src = cand + ((size_t)c << 11);
#pragma unroll
    for (int j = 0; j < 16; ++j) kc[j] = src[tid + (j << 7)];

    uint64 lastv = 0ull;
    for (int r = 0; r <= k; ++r) {
        uint64 m = ~0ull;
#pragma unroll
        for (int j = 0; j < 16; ++j) {
            const uint64 v = kc[j];
            if (v > lastv && v < m) m = v;
        }
#pragma unroll
        for (int off = 32; off > 0; off >>= 1) {
            uint64 o = __shfl_xor(m, off);
            if (o < m) m = o;
        }
        if (lane == 0) wmin[wv] = m;
        __syncthreads();
        if (tid == 0) s_win = wmin[0] < wmin[1] ? wmin[0] : wmin[1];
        __syncthreads();
        lastv = s_win;
    }
    const int pt = (int)(lastv & 0xFFFFFFFFull);   // k-th neighbor of center c

    if (tid < GDIM) gbuf[tid] = (tid < 3) ? p[3*pt + tid] : x[(pt << 6) + tid - 3];
    __syncthreads();
    float a = 0.f;
#pragma unroll
    for (int cc = 0; cc < GDIM; ++cc)
        a = fmaf(gbuf[cc], W[cc*C_OUT + tid], a);
    hbuf[(size_t)((c << 4) + k)*C_OUT + tid] = a;
}

// ---- finurow: 1 block x 128 (thread == channel). Stats from hbuf (round-11
// order), BN finalize in-register, maxpool urow from hbuf. Fallback c>=MAXC. ----
__global__ void __launch_bounds__(128) finurow_kernel(const float* __restrict__ p,
                                                      const float* __restrict__ x,
                                                      const float* __restrict__ W,
                                                      const float* __restrict__ gamma,
                                                      const float* __restrict__ beta,
                                                      const int* __restrict__ fps,
                                                      const int* __restrict__ meta,
                                                      const float* __restrict__ hbuf,
                                                      int* __restrict__ knn,
                                                      float* __restrict__ urow) {
    const int tid  = threadIdx.x;       // == channel
    const int lane = tid & 63;
    const int wv   = tid >> 6;
    const int nun  = meta[0], cs = meta[1], cl = meta[2];
    const int cmax = (nun < MAXC) ? nun : MAXC;

    __shared__ uint64 wmin[2];
    __shared__ uint64 s_win;
    __shared__ float  gbuf[GDIM + 1];

    float s_sum = 0.f, s_sq = 0.f;

    // stats from hbuf (same per-center ls/lq-then-weight order as round 11)
    for (int c = 0; c < cmax; ++c) {
        float ls = 0.f, lq = 0.f;
        const float* hb = hbuf + ((size_t)c << 4)*C_OUT;
#pragma unroll
        for (int k = 0; k < KNN; ++k) {
            const float a = hb[k*C_OUT + tid];
            ls += a;
            lq = fmaf(a, a, lq);
        }
        const float cf = (float)slot_count(c, nun, cs, cl, M_PTS);
        s_sum = fmaf(cf, ls, s_sum);
        s_sq  = fmaf(cf, lq, s_sq);
    }
    // fallback: centers beyond MAXC (never expected) — full-scan merge + h
    for (int c = MAXC; c < nun; ++c) {
        const int cpt = fps[c];
        const float qx = p[3*cpt], qy = p[3*cpt+1], qz = p[3*cpt+2];
        uint64 lastv = 0ull;
        for (int r = 0; r < KNN; ++r) {
            uint64 m = ~0ull;
            for (int i = tid; i < N_PTS; i += 128) {
                float dx = p[3*i]   - qx;
                float dy = p[3*i+1] - qy;
                float dz = p[3*i+2] - qz;
                float d  = fmaf(dx, dx, fmaf(dy, dy, dz*dz));
                uint64 v = ((uint64)dist_key(d) << 32) | (uint32)i;
                if (v > lastv && v < m) m = v;
            }
#pragma unroll
            for (int off = 32; off > 0; off >>= 1) {
                uint64 o = __shfl_xor(m, off);
                if (o < m) m = o;
            }
            if (lane == 0) wmin[wv] = m;
            __syncthreads();
            if (tid == 0) {
                uint64 w = wmin[0] < wmin[1] ? wmin[0] : wmin[1];
                s_win = w;
                knn[c*KNN + r] = (int)(w & 0xFFFFFFFFull);
            }
            __syncthreads();
            lastv = s_win;
        }
        float ls = 0.f, lq = 0.f;
#pragma unroll
        for (int k = 0; k < KNN; ++k) {
            const int pt = knn[c*KNN + k];
            if (tid < GDIM) gbuf[tid] = (tid < 3) ? p[3*pt + tid]
                                                  : x[(pt << 6) + tid - 3];
            __syncthreads();
            float a = 0.f;
#pragma unroll
            for (int cc = 0; cc < GDIM; ++cc)
                a = fmaf(gbuf[cc], W[cc*C_OUT + tid], a);
            ls += a;
            lq = fmaf(a, a, lq);
            __syncthreads();
        }
        const float cf = (float)slot_count(c, nun, cs, cl, M_PTS);
        s_sum = fmaf(cf, ls, s_sum);
        s_sq  = fmaf(cf, lq, s_sq);
    }

    // BN finalize in registers
    const float inv  = 1.0f / (float)(M_PTS * KNN);
    const float mean = s_sum * inv;
    const float var  = s_sq * inv - mean*mean;
    const float sc   = gamma[tid] * rsqrtf(var + BN_EPS);
    const float sh   = fmaf(-mean, sc, beta[tid]);

    // pooled unique rows
    for (int c = 0; c < cmax; ++c) {
        const float* hb = hbuf + ((size_t)c << 4)*C_OUT;
        float mx = 0.f;   // max_k relu(y) == max(0, max_k y)
#pragma unroll
        for (int k = 0; k < KNN; ++k)
            mx = fmaxf(mx, fmaf(hb[k*C_OUT + tid], sc, sh));
        urow[(size_t)c*C_OUT + tid] = mx;
    }
    for (int c = MAXC; c < nun; ++c) {
        float mx = 0.f;
#pragma unroll
        for (int k = 0; k < KNN; ++k) {
            const int pt = knn[c*KNN + k];
            if (tid < GDIM) gbuf[tid] = (tid < 3) ? p[3*pt + tid]
                                                  : x[(pt << 6) + tid - 3];
            __syncthreads();
            float a = 0.f;
#pragma unroll
            for (int cc = 0; cc < GDIM; ++cc)
                a = fmaf(gbuf[cc], W[cc*C_OUT + tid], a);
            mx = fmaxf(mx, fmaf(a, sc, sh));
            __syncthreads();
        }
        urow[(size_t)c*C_OUT + tid] = mx;
    }
}

// ---- broadcast: xout[m] = urow[slot(m)] for all m (pure float4 copy) ----------
__global__ void __launch_bounds__(256) bcast_kernel(const int* __restrict__ meta,
                                                    const float* __restrict__ urow,
                                                    float* __restrict__ xout) {
    const int nun = meta[0], cs = meta[1], cl = meta[2];
    const int idx = blockIdx.x * 256 + threadIdx.x;      // float4 index
    const int m = idx >> 5;                              // 32 float4 per row
    if (m >= M_PTS) return;
    const int c4 = idx & 31;
    const int sl = (m < nun) ? m : cs + (m - cs) % cl;
    float4 v = ((const float4*)urow)[(size_t)sl*32 + c4];
    ((float4*)xout)[(size_t)m*32 + c4] = v;
}

extern "C" void kernel_launch(void* const* d_in, const int* in_sizes, int n_in,
                              void* d_out, int out_size, void* d_ws, size_t ws_size,
                              hipStream_t stream) {
    (void)in_sizes; (void)n_in; (void)out_size; (void)ws_size;
    const float* p     = (const float*)d_in[0];
    const float* x     = (const float*)d_in[1];
    // d_in[2] = o (unused)
    const float* W     = (const float*)d_in[3];
    const float* gamma = (const float*)d_in[4];
    const float* beta  = (const float*)d_in[5];

    float* out  = (float*)d_out;
    float* newp = out;               // [M_PTS, 3]
    float* xout = out + M_PTS * 3;   // [M_PTS, C_OUT]

    char* ws = (char*)d_ws;
    int*    fps   = (int*)   (ws + OFF_FPS);
    int*    meta  = (int*)   (ws + OFF_META);
    int*    knn   = (int*)   (ws + OFF_KNN);
    uint64* cand  = (uint64*)(ws + OFF_CAND);
    float*  hbuf  = (float*) (ws + OFF_HBUF);
    float*  urow  = (float*) (ws + OFF_UROW);

    fps_chain_kernel<<<1, 1024, 0, stream>>>(p, fps, meta);
    knn_part_kernel <<<128, 1024, 0, stream>>>(p, fps, meta, cand, newp);
    hstats_kernel   <<<MAXC*KNN, 128, 0, stream>>>(p, x, W, meta, cand, hbuf);
    finurow_kernel  <<<1, 128, 0, stream>>>(p, x, W, gamma, beta, fps, meta,
                                            hbuf, knn, urow);
    bcast_kernel    <<<M_PTS*32/256, 256, 0, stream>>>(meta, urow, xout);
}

// Round 13
// 51.868 us; speedup vs baseline: 4.3793x; 1.1190x over previous
//
#include <hip/hip_runtime.h>

#define N_PTS 32768
#define M_PTS 8192      // N / STRIDE
#define C_IN  64
#define C_OUT 128
#define KNN   16
#define GDIM  67        // 3 + C_IN
#define BN_EPS 1e-5f
#define MAXC  64        // centers with candidate/hbuf fast path

// workspace offsets (bytes)
#define OFF_FPS   0u          // int[M_PTS] (only first nuniq used)
#define OFF_META  32768u      // int[8]: [0]=nuniq [1]=cycStart [2]=cycLen
#define OFF_KNN   33024u      // int[M_PTS*KNN] (fallback only)
#define OFF_CAND  557312u     // u64[MAXC*2048]
#define OFF_HBUF  1605888u    // float[MAXC*KNN*C_OUT]

typedef unsigned int uint32;
typedef unsigned long long uint64;

// multiplicity of unique slot s in the length-M periodic index sequence
__device__ __forceinline__ int slot_count(int s, int nun, int cs, int cl, int M) {
    if (s < cs) return 1;                 // pre-cycle slot: occurs once
    const int E = M - nun;                // extended (periodic) occurrences
    const int base = E / cl, rem = E % cl;
    const int start = (nun - cs) % cl;    // residue of first extended index
    int off = (s - cs) - start; if (off < 0) off += cl;
    return 1 + base + (off < rem ? 1 : 0);
}

__device__ __forceinline__ uint32 dist_key(float d) {
    uint32 u = __float_as_uint(d);
    return (u & 0x80000000u) ? ~u : (u | 0x80000000u);
}

// ---------------- FPS chain: serial argmax steps, float4 loads ----------------
__global__ void __launch_bounds__(1024) fps_chain_kernel(const float* __restrict__ p,
                                                         int* __restrict__ fps,
                                                         int* __restrict__ meta) {
    __shared__ int   s_chain[M_PTS];     // 32 KB
    __shared__ float wv_d[16];
    __shared__ int   wv_i[16];
    __shared__ int s_last, s_done, s_cs, s_win, s_found;
    const int tid  = threadIdx.x;
    const int lane = tid & 63;
    const int wid  = tid >> 6;
    const float4* p4 = (const float4*)p;

    if (tid == 0) { s_chain[0] = 0; s_last = 0; s_done = 0; s_cs = 0; }
    __syncthreads();

    int t = 1;
    while (t < M_PTS) {
        const int last = s_last;
        const float qx = p[3*last], qy = p[3*last+1], qz = p[3*last+2];
        float bd = -1.0f; int bi = 0;
#pragma unroll
        for (int j = 0; j < 8; ++j) {
            const int u = (j << 10) + tid;     // float4-triple index
            const int b = u << 2;              // base point (4 contiguous points)
            const float4 f0 = p4[3*u];
            const float4 f1 = p4[3*u + 1];
            const float4 f2 = p4[3*u + 2];
            const float xs[4] = {f0.x, f0.w, f1.z, f2.y};
            const float ys[4] = {f0.y, f1.x, f1.w, f2.z};
            const float zs[4] = {f0.z, f1.y, f2.x, f2.w};
#pragma unroll
            for (int q = 0; q < 4; ++q) {
                // match numpy: ((dx^2 + dy^2) + dz^2), no FMA contraction
                float dx = __fsub_rn(xs[q], qx);
                float dy = __fsub_rn(ys[q], qy);
                float dz = __fsub_rn(zs[q], qz);
                float d  = __fadd_rn(__fadd_rn(__fmul_rn(dx,dx), __fmul_rn(dy,dy)),
                                     __fmul_rn(dz,dz));
                if (d > bd) { bd = d; bi = b + q; }  // ascending idx keeps first tie
            }
        }
#pragma unroll
        for (int off = 32; off > 0; off >>= 1) {
            float od = __shfl_xor(bd, off);
            int   oi = __shfl_xor(bi, off);
            if (od > bd || (od == bd && oi < bi)) { bd = od; bi = oi; }
        }
        if (lane == 0) { wv_d[wid] = bd; wv_i[wid] = bi; }
        __syncthreads();
        if (wid == 0) {
            float rd = (lane < 16) ? wv_d[lane] : -1.0f;
            int   ri = (lane < 16) ? wv_i[lane] : 0x7fffffff;
#pragma unroll
            for (int off = 8; off > 0; off >>= 1) {
                float od = __shfl_xor(rd, off);
                int   oi = __shfl_xor(ri, off);
                if (od > rd || (od == rd && oi < ri)) { rd = od; ri = oi; }
            }
            if (lane == 0) { s_win = ri; s_found = -1; }
        }
        __syncthreads();
        const int nxt = s_win;
        for (int i = tid; i < t; i += 1024)
            if (s_chain[i] == nxt) s_found = i;
        __syncthreads();
        if (tid == 0) {
            if (s_found >= 0) { s_cs = s_found; s_done = 1; }
            else { s_chain[t] = nxt; s_last = nxt; }
        }
        __syncthreads();
        if (s_done) break;
        ++t;
    }

    if (tid == 0) {
        if (s_done) { meta[0] = t; meta[1] = s_cs; meta[2] = t - s_cs; }
        else        { meta[0] = M_PTS; meta[1] = 0; meta[2] = 1; }
    }
    const int nun = s_done ? t : M_PTS;
    for (int i = tid; i < nun; i += 1024) fps[i] = s_chain[i];
}

// ---- kNN phase A (+ parallel newp fill): 8 slices/center, float4 loads --------
__global__ void __launch_bounds__(1024) knn_part_kernel(const float* __restrict__ p,
                                                        const int* __restrict__ fps,
                                                        const int* __restrict__ meta,
                                                        uint64* __restrict__ cand,
                                                        float* __restrict__ newp) {
    const int tid   = threadIdx.x;
    const int lane  = tid & 63;
    const int wid   = tid >> 6;           // 16 waves
    const int slice = blockIdx.x & 7;
    const int c0    = blockIdx.x >> 3;    // 16 center groups
    const int nun   = meta[0];
    const int cs    = meta[1], cl = meta[2];
    const float4* p4 = (const float4*)p;

    // parallel newp fill
    for (int e = blockIdx.x * 1024 + tid; e < M_PTS; e += gridDim.x * 1024) {
        const int sl = (e < nun) ? e : cs + (e - cs) % cl;
        const int id = fps[sl];
        newp[3*e]   = p[3*id];
        newp[3*e+1] = p[3*id+1];
        newp[3*e+2] = p[3*id+2];
    }

    for (int c = c0; c < nun && c < MAXC; c += 16) {
        const int cpt = fps[c];
        const float qx = p[3*cpt], qy = p[3*cpt+1], qz = p[3*cpt+2];
        // this thread's 4 contiguous points within the slice
        const int bp = (slice << 12) + (tid << 2);
        const int u0 = (slice * 3072) + 3*tid;
        const float4 f0 = p4[u0], f1 = p4[u0+1], f2 = p4[u0+2];
        const float xs[4] = {f0.x, f0.w, f1.z, f2.y};
        const float ys[4] = {f0.y, f1.x, f1.w, f2.z};
        const float zs[4] = {f0.z, f1.y, f2.x, f2.w};

        uint64 pk4[4];
#pragma unroll
        for (int q = 0; q < 4; ++q) {
            float dx = xs[q] - qx;
            float dy = ys[q] - qy;
            float dz = zs[q] - qz;
            float d  = fmaf(dx, dx, fmaf(dy, dy, dz*dz));
            pk4[q] = ((uint64)dist_key(d) << 32) | (uint32)(bp + q);
        }

        uint64 lastv = 0ull;
        uint64* out = cand + ((size_t)c << 11) + (slice << 8) + (wid << 4);
        for (int r = 0; r < KNN; ++r) {
            uint64 m = ~0ull;
#pragma unroll
            for (int q = 0; q < 4; ++q) {
                const uint64 v = pk4[q];
                if (v > lastv && v < m) m = v;
            }
#pragma unroll
            for (int off = 32; off > 0; off >>= 1) {
                uint64 o = __shfl_xor(m, off);
                if (o < m) m = o;
            }
            if (lane == 0) out[r] = m;
            lastv = m;
        }
    }
}

// ---- hstats: grid = MAXC x KNN blocks, 128 threads (thread == channel).
// Block (c,k): merge cand[c] via k+1 threshold-extraction rounds (bit-identical
// selection), load g for the k-th neighbor, h = g.W, write hbuf[c][k][ch]. ----
__global__ void __launch_bounds__(128) hstats_kernel(const float* __restrict__ p,
                                                     const float* __restrict__ x,
                                                     const float* __restrict__ W,
                                                     const int* __restrict__ meta,
                                                     const uint64* __restrict__ cand,
                                                     float* __restrict__ hbuf) {
    const int c = blockIdx.x >> 4;
    const int k = blockIdx.x & 15;
    const int nun = meta[0];
    if (c >= nun || c >= MAXC) return;
    const int tid  = threadIdx.x;
    const int lane = tid & 63;
    const int wv   = tid >> 6;

    __shared__ uint64 wmin[2];
    __shared__ uint64 s_win;
    __shared__ float  gbuf[GDIM + 1];

    uint64 kc[16];
    const uint64* src = cand + ((size_t)c << 11);
#pragma unroll
    for (int j = 0; j < 16; ++j) kc[j] = src[tid + (j << 7)];

    uint64 lastv = 0ull;
    for (int r = 0; r <= k; ++r) {
        uint64 m = ~0ull;
#pragma unroll
        for (int j = 0; j < 16; ++j) {
            const uint64 v = kc[j];
            if (v > lastv && v < m) m = v;
        }
#pragma unroll
        for (int off = 32; off > 0; off >>= 1) {
            uint64 o = __shfl_xor(m, off);
            if (o < m) m = o;
        }
        if (lane == 0) wmin[wv] = m;
        __syncthreads();
        if (tid == 0) s_win = wmin[0] < wmin[1] ? wmin[0] : wmin[1];
        __syncthreads();
        lastv = s_win;
    }
    const int pt = (int)(lastv & 0xFFFFFFFFull);   // k-th neighbor of center c

    if (tid < GDIM) gbuf[tid] = (tid < 3) ? p[3*pt + tid] : x[(pt << 6) + tid - 3];
    __syncthreads();
    float a = 0.f;
#pragma unroll
    for (int cc = 0; cc < GDIM; ++cc)
        a = fmaf(gbuf[cc], W[cc*C_OUT + tid], a);
    hbuf[(size_t)((c << 4) + k)*C_OUT + tid] = a;
}

// ---- outall: 512 blocks x 256 threads, 16 rows/block. Per-block redundant
// stats from hbuf (identical fp order in every block -> identical scale/shift),
// BN into LDS, then rows maxpooled directly from hbuf and written as float4. ----
__global__ void __launch_bounds__(256) outall_kernel(const float* __restrict__ p,
                                                     const float* __restrict__ x,
                                                     const float* __restrict__ W,
                                                     const float* __restrict__ gamma,
                                                     const float* __restrict__ beta,
                                                     const int* __restrict__ fps,
                                                     const int* __restrict__ meta,
                                                     const float* __restrict__ hbuf,
                                                     int* __restrict__ knn,
                                                     float* __restrict__ xout) {
    const int tid = threadIdx.x;
    const int blk = blockIdx.x;
    const int nun = meta[0], cs = meta[1], cl = meta[2];
    const int cmax = (nun < MAXC) ? nun : MAXC;

    __shared__ float  ssc[128], ssh[128];
    __shared__ float  gbuf[GDIM + 1];
    __shared__ uint64 wred[4];
    __shared__ uint64 s_win;

    // ---- stats (threads 0..127, channel == tid), finurow order ----
    float s_sum = 0.f, s_sq = 0.f;
    if (tid < 128) {
        for (int c = 0; c < cmax; ++c) {
            const float* hb = hbuf + ((size_t)c << 4)*C_OUT;
            float ls = 0.f, lq = 0.f;
#pragma unroll
            for (int k = 0; k < KNN; ++k) {
                const float a = hb[k*C_OUT + tid];
                ls += a;
                lq = fmaf(a, a, lq);
            }
            const float cf = (float)slot_count(c, nun, cs, cl, M_PTS);
            s_sum = fmaf(cf, ls, s_sum);
            s_sq  = fmaf(cf, lq, s_sq);
        }
    }
    // fallback centers (never expected): cooperative scan -> knn -> h stats
    for (int c = MAXC; c < nun; ++c) {
        const int cpt = fps[c];
        const float qx = p[3*cpt], qy = p[3*cpt+1], qz = p[3*cpt+2];
        uint64 lastv = 0ull;
        for (int r = 0; r < KNN; ++r) {
            uint64 m = ~0ull;
            for (int i = tid; i < N_PTS; i += 256) {
                float dx = p[3*i]   - qx;
                float dy = p[3*i+1] - qy;
                float dz = p[3*i+2] - qz;
                float d  = fmaf(dx, dx, fmaf(dy, dy, dz*dz));
                uint64 v = ((uint64)dist_key(d) << 32) | (uint32)i;
                if (v > lastv && v < m) m = v;
            }
#pragma unroll
            for (int off = 32; off > 0; off >>= 1) {
                uint64 o = __shfl_xor(m, off);
                if (o < m) m = o;
            }
            if ((tid & 63) == 0) wred[tid >> 6] = m;
            __syncthreads();
            if (tid == 0) {
                uint64 w = wred[0];
                if (wred[1] < w) w = wred[1];
                if (wred[2] < w) w = wred[2];
                if (wred[3] < w) w = wred[3];
                s_win = w;
                knn[(size_t)c*KNN + r] = (int)(w & 0xFFFFFFFFull);
            }
            __syncthreads();
            lastv = s_win;
        }
        float ls = 0.f, lq = 0.f;
#pragma unroll
        for (int k = 0; k < KNN; ++k) {
            const int pt = knn[(size_t)c*KNN + k];
            if (tid < GDIM) gbuf[tid] = (tid < 3) ? p[3*pt + tid]
                                                  : x[(pt << 6) + tid - 3];
            __syncthreads();
            if (tid < 128) {
                float a = 0.f;
#pragma unroll
                for (int cc = 0; cc < GDIM; ++cc)
                    a = fmaf(gbuf[cc], W[cc*C_OUT + tid], a);
                ls += a;
                lq = fmaf(a, a, lq);
            }
            __syncthreads();
        }
        if (tid < 128) {
            const float cf = (float)slot_count(c, nun, cs, cl, M_PTS);
            s_sum = fmaf(cf, ls, s_sum);
            s_sq  = fmaf(cf, lq, s_sq);
        }
    }
    if (tid < 128) {
        const float inv  = 1.0f / (float)(M_PTS * KNN);
        const float mean = s_sum * inv;
        const float var  = s_sq * inv - mean*mean;
        const float sc   = gamma[tid] * rsqrtf(var + BN_EPS);
        ssc[tid] = sc;
        ssh[tid] = fmaf(-mean, sc, beta[tid]);
    }
    __syncthreads();

    // ---- rows: 16 per block, 32 float4-quads per row ----
#pragma unroll
    for (int it = 0; it < 2; ++it) {
        const int slot = it*256 + tid;
        const int m  = (blk << 4) + (slot >> 5);
        const int c4 = slot & 31;
        const int sl = (m < nun) ? m : cs + (m - cs) % cl;
        float4 o;
        float* ov = (float*)&o;
        if (sl < MAXC) {
            const float* hb = hbuf + ((size_t)sl << 4)*C_OUT;
#pragma unroll
            for (int cc = 0; cc < 4; ++cc) {
                const int ch = c4*4 + cc;
                const float sc = ssc[ch], sh = ssh[ch];
                float mx = 0.f;   // max_k relu(y) == max(0, max_k y)
#pragma unroll
                for (int k = 0; k < KNN; ++k)
                    mx = fmaxf(mx, fmaf(hb[k*C_OUT + ch], sc, sh));
                ov[cc] = mx;
            }
        } else {
            // dead-path recompute from knn (filled above for c >= MAXC)
#pragma unroll
            for (int cc = 0; cc < 4; ++cc) {
                const int ch = c4*4 + cc;
                const float sc = ssc[ch], sh = ssh[ch];
                float mx = 0.f;
                for (int k = 0; k < KNN; ++k) {
                    const int pt = knn[(size_t)sl*KNN + k];
                    float a = 0.f;
                    a = fmaf(p[3*pt],   W[0*C_OUT + ch], a);
                    a = fmaf(p[3*pt+1], W[1*C_OUT + ch], a);
                    a = fmaf(p[3*pt+2], W[2*C_OUT + ch], a);
                    for (int cx = 0; cx < C_IN; ++cx)
                        a = fmaf(x[(pt << 6) + cx], W[(3+cx)*C_OUT + ch], a);
                    mx = fmaxf(mx, fmaf(a, sc, sh));
                }
                ov[cc] = mx;
            }
        }
        ((float4*)xout)[(size_t)m*32 + c4] = o;
    }
}

extern "C" void kernel_launch(void* const* d_in, const int* in_sizes, int n_in,
                              void* d_out, int out_size, void* d_ws, size_t ws_size,
                              hipStream_t stream) {
    (void)in_sizes; (void)n_in; (void)out_size; (void)ws_size;
    const float* p     = (const float*)d_in[0];
    const float* x     = (const float*)d_in[1];
    // d_in[2] = o (unused)
    const float* W     = (const float*)d_in[3];
    const float* gamma = (const float*)d_in[4];
    const float* beta  = (const float*)d_in[5];

    float* out  = (float*)d_out;
    float* newp = out;               // [M_PTS, 3]
    float* xout = out + M_PTS * 3;   // [M_PTS, C_OUT]

    char* ws = (char*)d_ws;
    int*    fps   = (int*)   (ws + OFF_FPS);
    int*    meta  = (int*)   (ws + OFF_META);
    int*    knn   = (int*)   (ws + OFF_KNN);
    uint64* cand  = (uint64*)(ws + OFF_CAND);
    float*  hbuf  = (float*) (ws + OFF_HBUF);

    fps_chain_kernel<<<1, 1024, 0, stream>>>(p, fps, meta);
    knn_part_kernel <<<128, 1024, 0, stream>>>(p, fps, meta, cand, newp);
    hstats_kernel   <<<MAXC*KNN, 128, 0, stream>>>(p, x, W, meta, cand, hbuf);
    outall_kernel   <<<M_PTS/16, 256, 0, stream>>>(p, x, W, gamma, beta, fps,
                                                   meta, hbuf, knn, xout);
}

// Round 14
// 51.245 us; speedup vs baseline: 4.4325x; 1.0122x over previous
//
#include <hip/hip_runtime.h>

#define N_PTS 32768
#define M_PTS 8192      // N / STRIDE
#define C_IN  64
#define C_OUT 128
#define KNN   16
#define GDIM  67        // 3 + C_IN
#define BN_EPS 1e-5f
#define MAXC  64        // centers with candidate/hbuf fast path

// workspace offsets (bytes)
#define OFF_FPS   0u          // int[M_PTS] (only first nuniq used)
#define OFF_META  32768u      // int[8]: [0]=nuniq [1]=cycStart [2]=cycLen
#define OFF_KNN   33024u      // int[M_PTS*KNN] (fallback only)
#define OFF_CAND  557312u     // u64[MAXC*2048]
#define OFF_HBUF  1605888u    // float[MAXC*KNN*C_OUT]
#define OFF_SEED  2130176u    // u64[128] step-1 block winners

typedef unsigned int uint32;
typedef unsigned long long uint64;

// multiplicity of unique slot s in the length-M periodic index sequence
__device__ __forceinline__ int slot_count(int s, int nun, int cs, int cl, int M) {
    if (s < cs) return 1;                 // pre-cycle slot: occurs once
    const int E = M - nun;                // extended (periodic) occurrences
    const int base = E / cl, rem = E % cl;
    const int start = (nun - cs) % cl;    // residue of first extended index
    int off = (s - cs) - start; if (off < 0) off += cl;
    return 1 + base + (off < rem ? 1 : 0);
}

__device__ __forceinline__ uint32 dist_key(float d) {
    uint32 u = __float_as_uint(d);
    return (u & 0x80000000u) ? ~u : (u | 0x80000000u);
}

// ---- step1: wide argmax of d(p_i, p_0) — one point/thread, block winners ------
// Exact numpy distance chain; key = (d_bits<<32)|~i so max => (d max, idx min).
__global__ void __launch_bounds__(256) step1_kernel(const float* __restrict__ p,
                                                    uint64* __restrict__ seed) {
    const int i    = blockIdx.x * 256 + threadIdx.x;
    const int lane = threadIdx.x & 63;
    const int wv   = threadIdx.x >> 6;
    __shared__ uint64 wred[4];

    const float qx = p[0], qy = p[1], qz = p[2];
    float dx = __fsub_rn(p[3*i],   qx);
    float dy = __fsub_rn(p[3*i+1], qy);
    float dz = __fsub_rn(p[3*i+2], qz);
    float d  = __fadd_rn(__fadd_rn(__fmul_rn(dx,dx), __fmul_rn(dy,dy)),
                         __fmul_rn(dz,dz));
    uint64 key = ((uint64)__float_as_uint(d) << 32)
               | (uint32)(0xFFFFFFFFu - (uint32)i);
#pragma unroll
    for (int off = 32; off > 0; off >>= 1) {
        uint64 o = __shfl_xor(key, off);
        if (o > key) key = o;
    }
    if (lane == 0) wred[wv] = key;
    __syncthreads();
    if (threadIdx.x == 0) {
        uint64 m = wred[0];
        if (wred[1] > m) m = wred[1];
        if (wred[2] > m) m = wred[2];
        if (wred[3] > m) m = wred[3];
        seed[blockIdx.x] = m;
    }
}

// ---------------- FPS chain: step 1 from seed, then serial argmax steps --------
__global__ void __launch_bounds__(1024) fps_chain_kernel(const float* __restrict__ p,
                                                         const uint64* __restrict__ seed,
                                                         int* __restrict__ fps,
                                                         int* __restrict__ meta) {
    __shared__ int    s_chain[M_PTS];     // 32 KB
    __shared__ float  wv_d[16];
    __shared__ int    wv_i[16];
    __shared__ uint64 s_seed[2];
    __shared__ int s_last, s_done, s_cs, s_win, s_found;
    const int tid  = threadIdx.x;
    const int lane = tid & 63;
    const int wid  = tid >> 6;
    const float4* p4 = (const float4*)p;

    if (tid == 0) { s_chain[0] = 0; s_last = 0; s_done = 0; s_cs = 0; }
    __syncthreads();

    int t = 1;
    while (t < M_PTS) {
        if (t == 1) {
            // reduce the 128 precomputed block winners
            if (tid < 128) {
                uint64 k = seed[tid];
#pragma unroll
                for (int off = 32; off > 0; off >>= 1) {
                    uint64 o = __shfl_xor(k, off);
                    if (o > k) k = o;
                }
                if ((tid & 63) == 0) s_seed[tid >> 6] = k;
            }
            __syncthreads();
            if (tid == 0) {
                uint64 g = s_seed[0] > s_seed[1] ? s_seed[0] : s_seed[1];
                s_win = (int)(0xFFFFFFFFu - (uint32)(g & 0xFFFFFFFFull));
                s_found = -1;
            }
        } else {
            const int last = s_last;
            const float qx = p[3*last], qy = p[3*last+1], qz = p[3*last+2];
            float bd = -1.0f; int bi = 0;
#pragma unroll
            for (int j = 0; j < 8; ++j) {
                const int u = (j << 10) + tid;     // float4-triple index
                const int b = u << 2;              // base point (4 contiguous)
                const float4 f0 = p4[3*u];
                const float4 f1 = p4[3*u + 1];
                const float4 f2 = p4[3*u + 2];
                const float xs[4] = {f0.x, f0.w, f1.z, f2.y};
                const float ys[4] = {f0.y, f1.x, f1.w, f2.z};
                const float zs[4] = {f0.z, f1.y, f2.x, f2.w};
#pragma unroll
                for (int q = 0; q < 4; ++q) {
                    // match numpy: ((dx^2 + dy^2) + dz^2), no FMA contraction
                    float dx = __fsub_rn(xs[q], qx);
                    float dy = __fsub_rn(ys[q], qy);
                    float dz = __fsub_rn(zs[q], qz);
                    float d  = __fadd_rn(__fadd_rn(__fmul_rn(dx,dx),
                                                   __fmul_rn(dy,dy)),
                                         __fmul_rn(dz,dz));
                    if (d > bd) { bd = d; bi = b + q; }  // ascending idx: first tie
                }
            }
#pragma unroll
            for (int off = 32; off > 0; off >>= 1) {
                float od = __shfl_xor(bd, off);
                int   oi = __shfl_xor(bi, off);
                if (od > bd || (od == bd && oi < bi)) { bd = od; bi = oi; }
            }
            if (lane == 0) { wv_d[wid] = bd; wv_i[wid] = bi; }
            __syncthreads();
            if (wid == 0) {
                float rd = (lane < 16) ? wv_d[lane] : -1.0f;
                int   ri = (lane < 16) ? wv_i[lane] : 0x7fffffff;
#pragma unroll
                for (int off = 8; off > 0; off >>= 1) {
                    float od = __shfl_xor(rd, off);
                    int   oi = __shfl_xor(ri, off);
                    if (od > rd || (od == rd && oi < ri)) { rd = od; ri = oi; }
                }
                if (lane == 0) { s_win = ri; s_found = -1; }
            }
        }
        __syncthreads();
        const int nxt = s_win;
        for (int i = tid; i < t; i += 1024)
            if (s_chain[i] == nxt) s_found = i;
        __syncthreads();
        if (tid == 0) {
            if (s_found >= 0) { s_cs = s_found; s_done = 1; }
            else { s_chain[t] = nxt; s_last = nxt; }
        }
        __syncthreads();
        if (s_done) break;
        ++t;
    }

    if (tid == 0) {
        if (s_done) { meta[0] = t; meta[1] = s_cs; meta[2] = t - s_cs; }
        else        { meta[0] = M_PTS; meta[1] = 0; meta[2] = 1; }
    }
    const int nun = s_done ? t : M_PTS;
    for (int i = tid; i < nun; i += 1024) fps[i] = s_chain[i];
}

// ---- kNN phase A (+ parallel newp fill): 8 slices/center, float4 loads --------
__global__ void __launch_bounds__(1024) knn_part_kernel(const float* __restrict__ p,
                                                        const int* __restrict__ fps,
                                                        const int* __restrict__ meta,
                                                        uint64* __restrict__ cand,
                                                        float* __restrict__ newp) {
    const int tid   = threadIdx.x;
    const int lane  = tid & 63;
    const int wid   = tid >> 6;           // 16 waves
    const int slice = blockIdx.x & 7;
    const int c0    = blockIdx.x >> 3;    // 16 center groups
    const int nun   = meta[0];
    const int cs    = meta[1], cl = meta[2];
    const float4* p4 = (const float4*)p;

    // parallel newp fill
    for (int e = blockIdx.x * 1024 + tid; e < M_PTS; e += gridDim.x * 1024) {
        const int sl = (e < nun) ? e : cs + (e - cs) % cl;
        const int id = fps[sl];
        newp[3*e]   = p[3*id];
        newp[3*e+1] = p[3*id+1];
        newp[3*e+2] = p[3*id+2];
    }

    for (int c = c0; c < nun && c < MAXC; c += 16) {
        const int cpt = fps[c];
        const float qx = p[3*cpt], qy = p[3*cpt+1], qz = p[3*cpt+2];
        // this thread's 4 contiguous points within the slice
        const int bp = (slice << 12) + (tid << 2);
        const int u0 = (slice * 3072) + 3*tid;
        const float4 f0 = p4[u0], f1 = p4[u0+1], f2 = p4[u0+2];
        const float xs[4] = {f0.x, f0.w, f1.z, f2.y};
        const float ys[4] = {f0.y, f1.x, f1.w, f2.z};
        const float zs[4] = {f0.z, f1.y, f2.x, f2.w};

        uint64 pk4[4];
#pragma unroll
        for (int q = 0; q < 4; ++q) {
            float dx = xs[q] - qx;
            float dy = ys[q] - qy;
            float dz = zs[q] - qz;
            float d  = fmaf(dx, dx, fmaf(dy, dy, dz*dz));
            pk4[q] = ((uint64)dist_key(d) << 32) | (uint32)(bp + q);
        }

        uint64 lastv = 0ull;
        uint64* out = cand + ((size_t)c << 11) + (slice << 8) + (wid << 4);
        for (int r = 0; r < KNN; ++r) {
            uint64 m = ~0ull;
#pragma unroll
            for (int q = 0; q < 4; ++q) {
                const uint64 v = pk4[q];
                if (v > lastv && v < m) m = v;
            }
#pragma unroll
            for (int off = 32; off > 0; off >>= 1) {
                uint64 o = __shfl_xor(m, off);
                if (o < m) m = o;
            }
            if (lane == 0) out[r] = m;
            lastv = m;
        }
    }
}

// ---- hstats: grid = MAXC x KNN blocks, 128 threads (thread == channel).
// Block (c,k): merge cand[c] via k+1 threshold-extraction rounds (bit-identical
// selection), load g for the k-th neighbor, h = g.W, write hbuf[c][k][ch]. ----
__global__ void __launch_bounds__(128) hstats_kernel(const float* __restrict__ p,
                                                     const float* __restrict__ x,
                                                     const float* __restrict__ W,
                                                     const int* __restrict__ meta,
                                                     const uint64* __restrict__ cand,
                                                     float* __restrict__ hbuf) {
    const int c = blockIdx.x >> 4;
    const int k = blockIdx.x & 15;
    const int nun = meta[0];
    if (c >= nun || c >= MAXC) return;
    const int tid  = threadIdx.x;
    const int lane = tid & 63;
    const int wv   = tid >> 6;

    __shared__ uint64 wmin[2];
    __shared__ uint64 s_win;
    __shared__ float  gbuf[GDIM + 1];

    uint64 kc[16];
    const uint64* src = cand + ((size_t)c << 11);
#pragma unroll
    for (int j = 0; j < 16; ++j) kc[j] = src[tid + (j << 7)];

    uint64 lastv = 0ull;
    for (int r = 0; r <= k; ++r) {
        uint64 m = ~0ull;
#pragma unroll
        for (int j = 0; j < 16; ++j) {
            const uint64 v = kc[j];
            if (v > lastv && v < m) m = v;
        }
#pragma unroll
        for (int off = 32; off > 0; off >>= 1) {
            uint64 o = __shfl_xor(m, off);
            if (o < m) m = o;
        }
        if (lane == 0) wmin[wv] = m;
        __syncthreads();
        if (tid == 0) s_win = wmin[0] < wmin[1] ? wmin[0] : wmin[1];
        __syncthreads();
        lastv = s_win;
    }
    const int pt = (int)(lastv & 0xFFFFFFFFull);   // k-th neighbor of center c

    if (tid < GDIM) gbuf[tid] = (tid < 3) ? p[3*pt + tid] : x[(pt << 6) + tid - 3];
    __syncthreads();
    float a = 0.f;
#pragma unroll
    for (int cc = 0; cc < GDIM; ++cc)
        a = fmaf(gbuf[cc], W[cc*C_OUT + tid], a);
    hbuf[(size_t)((c << 4) + k)*C_OUT + tid] = a;
}

// ---- outall: 512 blocks x 256 threads, 16 rows/block. Per-block redundant
// stats from hbuf (identical fp order in every block -> identical scale/shift),
// BN into LDS, then rows maxpooled directly from hbuf and written as float4. ----
__global__ void __launch_bounds__(256) outall_kernel(const float* __restrict__ p,
                                                     const float* __restrict__ x,
                                                     const float* __restrict__ W,
                                                     const float* __restrict__ gamma,
                                                     const float* __restrict__ beta,
                                                     const int* __restrict__ fps,
                                                     const int* __restrict__ meta,
                                                     const float* __restrict__ hbuf,
                                                     int* __restrict__ knn,
                                                     float* __restrict__ xout) {
    const int tid = threadIdx.x;
    const int blk = blockIdx.x;
    const int nun = meta[0], cs = meta[1], cl = meta[2];
    const int cmax = (nun < MAXC) ? nun : MAXC;

    __shared__ float  ssc[128], ssh[128];
    __shared__ float  gbuf[GDIM + 1];
    __shared__ uint64 wred[4];
    __shared__ uint64 s_win;

    // ---- stats (threads 0..127, channel == tid) ----
    float s_sum = 0.f, s_sq = 0.f;
    if (tid < 128) {
        for (int c = 0; c < cmax; ++c) {
            const float* hb = hbuf + ((size_t)c << 4)*C_OUT;
            float ls = 0.f, lq = 0.f;
#pragma unroll
            for (int k = 0; k < KNN; ++k) {
                const float a = hb[k*C_OUT + tid];
                ls += a;
                lq = fmaf(a, a, lq);
            }
            const float cf = (float)slot_count(c, nun, cs, cl, M_PTS);
            s_sum = fmaf(cf, ls, s_sum);
            s_sq  = fmaf(cf, lq, s_sq);
        }
    }
    // fallback centers (never expected): cooperative scan -> knn -> h stats
    for (int c = MAXC; c < nun; ++c) {
        const int cpt = fps[c];
        const float qx = p[3*cpt], qy = p[3*cpt+1], qz = p[3*cpt+2];
        uint64 lastv = 0ull;
        for (int r = 0; r < KNN; ++r) {
            uint64 m = ~0ull;
            for (int i = tid; i < N_PTS; i += 256) {
                float dx = p[3*i]   - qx;
                float dy = p[3*i+1] - qy;
                float dz = p[3*i+2] - qz;
                float d  = fmaf(dx, dx, fmaf(dy, dy, dz*dz));
                uint64 v = ((uint64)dist_key(d) << 32) | (uint32)i;
                if (v > lastv && v < m) m = v;
            }
#pragma unroll
            for (int off = 32; off > 0; off >>= 1) {
                uint64 o = __shfl_xor(m, off);
                if (o < m) m = o;
            }
            if ((tid & 63) == 0) wred[tid >> 6] = m;
            __syncthreads();
            if (tid == 0) {
                uint64 w = wred[0];
                if (wred[1] < w) w = wred[1];
                if (wred[2] < w) w = wred[2];
                if (wred[3] < w) w = wred[3];
                s_win = w;
                knn[(size_t)c*KNN + r] = (int)(w & 0xFFFFFFFFull);
            }
            __syncthreads();
            lastv = s_win;
        }
        float ls = 0.f, lq = 0.f;
#pragma unroll
        for (int k = 0; k < KNN; ++k) {
            const int pt = knn[(size_t)c*KNN + k];
            if (tid < GDIM) gbuf[tid] = (tid < 3) ? p[3*pt + tid]
                                                  : x[(pt << 6) + tid - 3];
            __syncthreads();
            if (tid < 128) {
                float a = 0.f;
#pragma unroll
                for (int cc = 0; cc < GDIM; ++cc)
                    a = fmaf(gbuf[cc], W[cc*C_OUT + tid], a);
                ls += a;
                lq = fmaf(a, a, lq);
            }
            __syncthreads();
        }
        if (tid < 128) {
            const float cf = (float)slot_count(c, nun, cs, cl, M_PTS);
            s_sum = fmaf(cf, ls, s_sum);
            s_sq  = fmaf(cf, lq, s_sq);
        }
    }
    if (tid < 128) {
        const float inv  = 1.0f / (float)(M_PTS * KNN);
        const float mean = s_sum * inv;
        const float var  = s_sq * inv - mean*mean;
        const float sc   = gamma[tid] * rsqrtf(var + BN_EPS);
        ssc[tid] = sc;
        ssh[tid] = fmaf(-mean, sc, beta[tid]);
    }
    __syncthreads();

    // ---- rows: 16 per block, 32 float4-quads per row ----
#pragma unroll
    for (int it = 0; it < 2; ++it) {
        const int slot = it*256 + tid;
        const int m  = (blk << 4) + (slot >> 5);
        const int c4 = slot & 31;
        const int sl = (m < nun) ? m : cs + (m - cs) % cl;
        float4 o;
        float* ov = (float*)&o;
        if (sl < MAXC) {
            const float* hb = hbuf + ((size_t)sl << 4)*C_OUT;
#pragma unroll
            for (int cc = 0; cc < 4; ++cc) {
                const int ch = c4*4 + cc;
                const float sc = ssc[ch], sh = ssh[ch];
                float mx = 0.f;   // max_k relu(y) == max(0, max_k y)
#pragma unroll
                for (int k = 0; k < KNN; ++k)
                    mx = fmaxf(mx, fmaf(hb[k*C_OUT + ch], sc, sh));
                ov[cc] = mx;
            }
        } else {
            // dead-path recompute from knn (filled above for c >= MAXC)
#pragma unroll
            for (int cc = 0; cc < 4; ++cc) {
                const int ch = c4*4 + cc;
                const float sc = ssc[ch], sh = ssh[ch];
                float mx = 0.f;
                for (int k = 0; k < KNN; ++k) {
                    const int pt = knn[(size_t)sl*KNN + k];
                    float a = 0.f;
                    a = fmaf(p[3*pt],   W[0*C_OUT + ch], a);
                    a = fmaf(p[3*pt+1], W[1*C_OUT + ch], a);
                    a = fmaf(p[3*pt+2], W[2*C_OUT + ch], a);
                    for (int cx = 0; cx < C_IN; ++cx)
                        a = fmaf(x[(pt << 6) + cx], W[(3+cx)*C_OUT + ch], a);
                    mx = fmaxf(mx, fmaf(a, sc, sh));
                }
                ov[cc] = mx;
            }
        }
        ((float4*)xout)[(size_t)m*32 + c4] = o;
    }
}

extern "C" void kernel_launch(void* const* d_in, const int* in_sizes, int n_in,
                              void* d_out, int out_size, void* d_ws, size_t ws_size,
                              hipStream_t stream) {
    (void)in_sizes; (void)n_in; (void)out_size; (void)ws_size;
    const float* p     = (const float*)d_in[0];
    const float* x     = (const float*)d_in[1];
    // d_in[2] = o (unused)
    const float* W     = (const float*)d_in[3];
    const float* gamma = (const float*)d_in[4];
    const float* beta  = (const float*)d_in[5];

    float* out  = (float*)d_out;
    float* newp = out;               // [M_PTS, 3]
    float* xout = out + M_PTS * 3;   // [M_PTS, C_OUT]

    char* ws = (char*)d_ws;
    int*    fps   = (int*)   (ws + OFF_FPS);
    int*    meta  = (int*)   (ws + OFF_META);
    int*    knn   = (int*)   (ws + OFF_KNN);
    uint64* cand  = (uint64*)(ws + OFF_CAND);
    float*  hbuf  = (float*) (ws + OFF_HBUF);
    uint64* seed  = (uint64*)(ws + OFF_SEED);

    step1_kernel    <<<N_PTS/256, 256, 0, stream>>>(p, seed);
    fps_chain_kernel<<<1, 1024, 0, stream>>>(p, seed, fps, meta);
    knn_part_kernel <<<128, 1024, 0, stream>>>(p, fps, meta, cand, newp);
    hstats_kernel   <<<MAXC*KNN, 128, 0, stream>>>(p, x, W, meta, cand, hbuf);
    outall_kernel   <<<M_PTS/16, 256, 0, stream>>>(p, x, W, gamma, beta, fps,
                                                   meta, hbuf, knn, xout);
}